// Round 1
// baseline (311.077 us; speedup 1.0000x reference)
//
#include <hip/hip_runtime.h>
#include <hip/hip_bf16.h>
#include <math.h>

#define CDIM 64
#define BATCH 2
#define TK 128

typedef __bf16 bf16x8 __attribute__((ext_vector_type(8)));
typedef __bf16 bf16x4 __attribute__((ext_vector_type(4)));
typedef float f32x4 __attribute__((ext_vector_type(4)));

// ---------------------------------------------------------------------------
// Stage 1: fused 1x1-conv projections.
//   Q[b][n][c] = (wa x + ba)^T   (bf16, [N,C] row-major  -> MFMA B-operand reads)
//   K[b][n][c] = (wb x + bb)^T   (bf16, [N,C] row-major  -> MFMA A-operand reads)
//   V[b][c][n] = BN(wm x + bm)   (bf16, [C,N] row-major  -> MFMA A-operand reads)
// grid (N/64, 3, B), block 256. which = blockIdx.y selects the projection.
// ---------------------------------------------------------------------------
__global__ __launch_bounds__(256) void gfa_stage1(
    const float* __restrict__ feature,
    const float* __restrict__ wa, const float* __restrict__ ba,
    const float* __restrict__ wb, const float* __restrict__ bb,
    const float* __restrict__ wm, const float* __restrict__ bm,
    const float* __restrict__ gma, const float* __restrict__ bta,
    const float* __restrict__ mean, const float* __restrict__ var,
    __bf16* __restrict__ Q, __bf16* __restrict__ K, __bf16* __restrict__ V,
    int N)
{
    const int tid = threadIdx.x;
    const int n0 = blockIdx.x * 64;
    const int which = blockIdx.y;
    const int b = blockIdx.z;

    __shared__ float xs[CDIM * 64];   // x tile [c][n], row stride 64 -> 2-way (free)
    const float* fb = feature + (size_t)b * CDIM * N;
#pragma unroll
    for (int p = 0; p < 4; p++) {
        int idx = p * 256 + tid;                 // float4 index
        int c = idx >> 4, n4 = (idx & 15) << 2;
        *(float4*)&xs[c * 64 + n4] = *(const float4*)&fb[(size_t)c * N + n0 + n4];
    }
    __syncthreads();

    const int nl = tid & 63;
    const int og = __builtin_amdgcn_readfirstlane(tid >> 6);  // wave-uniform o-group

    float xcol[CDIM];
#pragma unroll
    for (int c = 0; c < CDIM; c++) xcol[c] = xs[c * 64 + nl];

    const float* w    = (which == 0) ? wa : (which == 1) ? wb : wm;
    const float* bias = (which == 0) ? ba : (which == 1) ? bb : bm;

    float acc[16];
#pragma unroll
    for (int i = 0; i < 16; i++) {
        const float* wrow = w + (og * 16 + i) * 64;  // uniform -> s_load
        float a = 0.f;
#pragma unroll
        for (int c = 0; c < CDIM; c++) a = fmaf(wrow[c], xcol[c], a);
        acc[i] = a + bias[og * 16 + i];
    }

    if (which < 2) {
        __bf16* O = (which == 0 ? Q : K)
                  + (size_t)b * N * CDIM + (size_t)(n0 + nl) * CDIM + og * 16;
        union { __bf16 h[16]; int4 q[2]; } u;
#pragma unroll
        for (int i = 0; i < 16; i++) u.h[i] = (__bf16)acc[i];
        ((int4*)O)[0] = u.q[0];
        ((int4*)O)[1] = u.q[1];
    } else {
#pragma unroll
        for (int i = 0; i < 16; i++) {
            int c = og * 16 + i;
            float s = gma[c] * rsqrtf(var[c] + 1e-5f);
            float v = (acc[i] - mean[c]) * s + bta[c];
            V[(size_t)b * CDIM * N + (size_t)c * N + n0 + nl] = (__bf16)v;
        }
    }
}

// ---------------------------------------------------------------------------
// Stage 2: flash attention, transposed-logits formulation.
//   S^T[kv][q] = K[kv][:]·Q[q][:]   (A = K-tile, B = Q-frags in regs)
//   softmax over kv = over C-layout ROWS -> stats per lane (col q), 2 shuffles
//   out^T[c][q] += V[c][kv]·P^T[kv][q]  (A = V-tile, B = P strip via LDS)
// grid (N/64, B), block 256 (4 waves x 16 q-columns).
// LDS row strides padded: Kt 144B, Vt/P 272B -> <=2-way bank aliasing (free).
// ---------------------------------------------------------------------------
__global__ __launch_bounds__(256) void gfa_stage2(
    const float* __restrict__ feature, const float* __restrict__ alpha_p,
    const __bf16* __restrict__ Q, const __bf16* __restrict__ K,
    const __bf16* __restrict__ V, float* __restrict__ out, int N)
{
    const int tid  = threadIdx.x;
    const int w    = tid >> 6;
    const int lane = tid & 63;
    const int l15  = lane & 15;
    const int quad = lane >> 4;
    const int b    = blockIdx.y;
    const int qb   = blockIdx.x * 64 + w * 16;   // wave's q-column base

    __shared__ __align__(16) char lds[18432 + 17408 + 17408];  // 52 KB
    char* Kt = lds;                           // [128][144B]  K tile [kv][c]
    char* Vt = lds + 18432;                   // [64][272B]   V tile [c][kv]
    char* Pw = lds + 18432 + 17408 + w * 4352; // per-wave P strip [16 q][272B]

    const __bf16* Qg = Q + (size_t)b * N * CDIM;
    const __bf16* Kg = K + (size_t)b * N * CDIM;
    const __bf16* Vg = V + (size_t)b * CDIM * N;

    // Q fragments (B-operand: lane n=q reads Q[q][kc*32 + quad*8 .. +7]), loop-invariant
    bf16x8 qf[2];
#pragma unroll
    for (int kc = 0; kc < 2; kc++)
        qf[kc] = *(const bf16x8*)(Qg + (size_t)(qb + l15) * CDIM + kc * 32 + quad * 8);

    f32x4 acc[4];   // out^T tiles tc: row c = 16*tc + quad*4 + r, col q = qb + l15
#pragma unroll
    for (int tc = 0; tc < 4; tc++) acc[tc] = (f32x4){0.f, 0.f, 0.f, 0.f};
    float m_run = -INFINITY, l_run = 0.f;

    for (int kv0 = 0; kv0 < N; kv0 += TK) {
        __syncthreads();
        // stage K tile: 128 rows x 128B, pad to 144B stride
#pragma unroll
        for (int p = 0; p < 4; p++) {
            int idx = p * 256 + tid;
            int r = idx >> 3, c16 = idx & 7;
            *(int4*)(Kt + r * 144 + c16 * 16) =
                *(const int4*)((const char*)Kg + (size_t)(kv0 + r) * CDIM * 2 + c16 * 16);
        }
        // stage V tile: 64 rows x 256B, pad to 272B stride
#pragma unroll
        for (int p = 0; p < 4; p++) {
            int idx = p * 256 + tid;
            int r = idx >> 4, c16 = idx & 15;
            *(int4*)(Vt + r * 272 + c16 * 16) =
                *(const int4*)((const char*)Vg + ((size_t)r * N + kv0) * 2 + c16 * 16);
        }
        __syncthreads();

        // S^T tiles: rows kv = 16t + quad*4 + r, col q
        f32x4 lt[8];
#pragma unroll
        for (int t = 0; t < 8; t++) {
            f32x4 a = (f32x4){0.f, 0.f, 0.f, 0.f};
#pragma unroll
            for (int kc = 0; kc < 2; kc++) {
                bf16x8 kf = *(const bf16x8*)(Kt + (16 * t + l15) * 144 + kc * 64 + quad * 16);
                a = __builtin_amdgcn_mfma_f32_16x16x32_bf16(kf, qf[kc], a, 0, 0, 0);
            }
            lt[t] = a;
        }

        // online softmax over kv (rows): in-lane + xor16/xor32
        float mx = -INFINITY;
#pragma unroll
        for (int t = 0; t < 8; t++)
#pragma unroll
            for (int r = 0; r < 4; r++) mx = fmaxf(mx, lt[t][r]);
        mx = fmaxf(mx, __shfl_xor(mx, 16));
        mx = fmaxf(mx, __shfl_xor(mx, 32));
        float m_new = fmaxf(m_run, mx);
        float scale = __expf(m_run - m_new);

        float s = 0.f;
#pragma unroll
        for (int t = 0; t < 8; t++) {
            bf16x4 pb;
#pragma unroll
            for (int r = 0; r < 4; r++) {
                float p = __expf(lt[t][r] - m_new);
                s += p;
                pb[r] = (__bf16)p;
            }
            // P strip [q][kv]: 4 consecutive kv (regs) -> one ds_write_b64
            *(bf16x4*)(Pw + l15 * 272 + (16 * t + quad * 4) * 2) = pb;
        }
        s += __shfl_xor(s, 16);
        s += __shfl_xor(s, 32);
        l_run = l_run * scale + s;
        m_run = m_new;
#pragma unroll
        for (int tc = 0; tc < 4; tc++)
#pragma unroll
            for (int r = 0; r < 4; r++) acc[tc][r] *= scale;

        // PV: out^T[c][q] += V[c][kv] * P^T[kv][q]
#pragma unroll
        for (int ks = 0; ks < 4; ks++) {
            bf16x8 pf = *(const bf16x8*)(Pw + l15 * 272 + ks * 64 + quad * 16);
#pragma unroll
            for (int tc = 0; tc < 4; tc++) {
                bf16x8 vf = *(const bf16x8*)(Vt + (16 * tc + l15) * 272 + ks * 64 + quad * 16);
                acc[tc] = __builtin_amdgcn_mfma_f32_16x16x32_bf16(vf, pf, acc[tc], 0, 0, 0);
            }
        }
    }

    // epilogue: out = 2*feature + 2*alpha * acc/l
    float a2 = 2.f * alpha_p[0];
    float inv_l = 1.f / l_run;               // per q column (lane-resident)
    const float* fb = feature + (size_t)b * CDIM * N;
    float* ob = out + (size_t)b * CDIM * N;
    int nq = qb + l15;
#pragma unroll
    for (int tc = 0; tc < 4; tc++)
#pragma unroll
        for (int r = 0; r < 4; r++) {
            int c = 16 * tc + quad * 4 + r;
            float f = fb[(size_t)c * N + nq];
            ob[(size_t)c * N + nq] = 2.f * f + a2 * acc[tc][r] * inv_l;
        }
}

// ---------------------------------------------------------------------------
extern "C" void kernel_launch(void* const* d_in, const int* in_sizes, int n_in,
                              void* d_out, int out_size, void* d_ws, size_t ws_size,
                              hipStream_t stream) {
    const float* feature = (const float*)d_in[0];
    const float* wa   = (const float*)d_in[1];
    const float* ba   = (const float*)d_in[2];
    const float* wb   = (const float*)d_in[3];
    const float* bb   = (const float*)d_in[4];
    const float* wm   = (const float*)d_in[5];
    const float* bm   = (const float*)d_in[6];
    const float* gma  = (const float*)d_in[7];
    const float* bta  = (const float*)d_in[8];
    const float* mean = (const float*)d_in[9];
    const float* var  = (const float*)d_in[10];
    const float* alpha = (const float*)d_in[11];
    const int N = in_sizes[0] / (BATCH * CDIM);   // 8192

    __bf16* Q = (__bf16*)d_ws;
    __bf16* K = Q + (size_t)BATCH * N * CDIM;
    __bf16* V = K + (size_t)BATCH * N * CDIM;

    dim3 g1(N / 64, 3, BATCH);
    gfa_stage1<<<g1, 256, 0, stream>>>(feature, wa, ba, wb, bb, wm, bm,
                                       gma, bta, mean, var, Q, K, V, N);
    dim3 g2(N / 64, BATCH);
    gfa_stage2<<<g2, 256, 0, stream>>>(feature, alpha, Q, K, V, (float*)d_out, N);
}

// Round 2
// 173.894 us; speedup vs baseline: 1.7889x; 1.7889x over previous
//
#include <hip/hip_runtime.h>
#include <hip/hip_bf16.h>
#include <math.h>

#define CDIM 64
#define BATCH 2
#define KSPLIT 8
#define TK 64

typedef __bf16 bf16x8 __attribute__((ext_vector_type(8)));
typedef __bf16 bf16x4 __attribute__((ext_vector_type(4)));
typedef float f32x4 __attribute__((ext_vector_type(4)));

// ---------------------------------------------------------------------------
// Stage 1: fused 1x1-conv projections via MFMA, hi/lo bf16 split for fp32-level
// precision:  P = (Whi+Wlo)·(Xhi+Xlo) ≈ Whi·Xhi + Wlo·Xhi + Whi·Xlo.
//   Q[n][c] (bf16), K[n][c] (bf16), V[c][n] (bf16, BN folded)
// grid (N/128, 3, B), block 256 (4 waves, 32 n each).
// LDS: Xs fp32 [64][130] (stride 130: quads land on distinct banks),
//      Whi/Wlo bf16 [64][72] (b128 A-frag reads ~conflict-free).
// ---------------------------------------------------------------------------
__global__ __launch_bounds__(256) void gfa_stage1(
    const float* __restrict__ feature,
    const float* __restrict__ wa, const float* __restrict__ ba,
    const float* __restrict__ wb, const float* __restrict__ bb,
    const float* __restrict__ wm, const float* __restrict__ bm,
    const float* __restrict__ gma, const float* __restrict__ bta,
    const float* __restrict__ mean, const float* __restrict__ var,
    __bf16* __restrict__ Q, __bf16* __restrict__ K, __bf16* __restrict__ V,
    int N)
{
    const int tid  = threadIdx.x;
    const int w    = tid >> 6;
    const int lane = tid & 63;
    const int l15  = lane & 15;
    const int quad = lane >> 4;
    const int n0    = blockIdx.x * 128;
    const int which = blockIdx.y;
    const int b     = blockIdx.z;

    __shared__ float  Xs[64 * 130];
    __shared__ __bf16 Whi[64 * 72];
    __shared__ __bf16 Wlo[64 * 72];

    const float* wsel = (which == 0) ? wa : (which == 1) ? wb : wm;
    const float* bsel = (which == 0) ? ba : (which == 1) ? bb : bm;

    // stage X tile [64 c][128 n] fp32 (float2 stores: stride 130 keeps 8B align)
    const float* fb = feature + (size_t)b * CDIM * N;
#pragma unroll
    for (int p = 0; p < 8; p++) {
        int idx = p * 256 + tid;
        int c = idx >> 5, n4 = (idx & 31) << 2;
        float4 v = *(const float4*)&fb[(size_t)c * N + n0 + n4];
        *(float2*)&Xs[c * 130 + n4]     = make_float2(v.x, v.y);
        *(float2*)&Xs[c * 130 + n4 + 2] = make_float2(v.z, v.w);
    }
    // stage W hi/lo
#pragma unroll
    for (int p = 0; p < 4; p++) {
        int idx = p * 256 + tid;
        int o = idx >> 4, c4 = (idx & 15) << 2;
        float4 v = *(const float4*)&wsel[o * 64 + c4];
        bf16x4 hi, lo;
        float vv[4] = {v.x, v.y, v.z, v.w};
#pragma unroll
        for (int r = 0; r < 4; r++) {
            hi[r] = (__bf16)vv[r];
            lo[r] = (__bf16)(vv[r] - (float)hi[r]);
        }
        *(bf16x4*)&Whi[o * 72 + c4] = hi;
        *(bf16x4*)&Wlo[o * 72 + c4] = lo;
    }
    __syncthreads();

    // B-fragments: X hi/lo for this wave's 32 n-columns
    const int nb = w * 32;
    bf16x8 xh[2][2], xl[2][2];   // [nt][kc]
#pragma unroll
    for (int nt = 0; nt < 2; nt++)
#pragma unroll
        for (int kc = 0; kc < 2; kc++) {
#pragma unroll
            for (int j = 0; j < 8; j++) {
                float xv = Xs[(kc * 32 + quad * 8 + j) * 130 + nb + nt * 16 + l15];
                __bf16 h = (__bf16)xv;
                xh[nt][kc][j] = h;
                xl[nt][kc][j] = (__bf16)(xv - (float)h);
            }
        }

    f32x4 acc[4][2];   // [ot][nt]
#pragma unroll
    for (int ot = 0; ot < 4; ot++)
#pragma unroll
        for (int nt = 0; nt < 2; nt++) acc[ot][nt] = (f32x4){0.f, 0.f, 0.f, 0.f};

#pragma unroll
    for (int ot = 0; ot < 4; ot++) {
        bf16x8 wh[2], wl[2];
#pragma unroll
        for (int kc = 0; kc < 2; kc++) {
            wh[kc] = *(const bf16x8*)&Whi[(ot * 16 + l15) * 72 + kc * 32 + quad * 8];
            wl[kc] = *(const bf16x8*)&Wlo[(ot * 16 + l15) * 72 + kc * 32 + quad * 8];
        }
#pragma unroll
        for (int nt = 0; nt < 2; nt++)
#pragma unroll
            for (int kc = 0; kc < 2; kc++) {
                acc[ot][nt] = __builtin_amdgcn_mfma_f32_16x16x32_bf16(wh[kc], xh[nt][kc], acc[ot][nt], 0, 0, 0);
                acc[ot][nt] = __builtin_amdgcn_mfma_f32_16x16x32_bf16(wl[kc], xh[nt][kc], acc[ot][nt], 0, 0, 0);
                acc[ot][nt] = __builtin_amdgcn_mfma_f32_16x16x32_bf16(wh[kc], xl[nt][kc], acc[ot][nt], 0, 0, 0);
            }
    }

    // epilogue: C-layout row = o = ot*16 + quad*4 + r, col n = l15
    if (which < 2) {
        __bf16* O = (which == 0 ? Q : K) + (size_t)b * N * CDIM;
#pragma unroll
        for (int ot = 0; ot < 4; ot++) {
            int o0 = ot * 16 + quad * 4;
            float4 b4 = *(const float4*)&bsel[o0];
            float bv[4] = {b4.x, b4.y, b4.z, b4.w};
#pragma unroll
            for (int nt = 0; nt < 2; nt++) {
                int n = n0 + nb + nt * 16 + l15;
                bf16x4 pk;
#pragma unroll
                for (int r = 0; r < 4; r++) pk[r] = (__bf16)(acc[ot][nt][r] + bv[r]);
                *(bf16x4*)&O[(size_t)n * CDIM + o0] = pk;
            }
        }
    } else {
        __bf16* Vb = V + (size_t)b * CDIM * N;
#pragma unroll
        for (int ot = 0; ot < 4; ot++) {
            int o0 = ot * 16 + quad * 4;
            float4 b4 = *(const float4*)&bsel[o0];
            float4 m4 = *(const float4*)&mean[o0];
            float4 v4 = *(const float4*)&var[o0];
            float4 g4 = *(const float4*)&gma[o0];
            float4 t4 = *(const float4*)&bta[o0];
            float bv[4] = {b4.x, b4.y, b4.z, b4.w};
            float mv[4] = {m4.x, m4.y, m4.z, m4.w};
            float vv[4] = {v4.x, v4.y, v4.z, v4.w};
            float gv[4] = {g4.x, g4.y, g4.z, g4.w};
            float tv[4] = {t4.x, t4.y, t4.z, t4.w};
#pragma unroll
            for (int nt = 0; nt < 2; nt++) {
                int n = n0 + nb + nt * 16 + l15;
#pragma unroll
                for (int r = 0; r < 4; r++) {
                    float s = gv[r] * rsqrtf(vv[r] + 1e-5f);
                    float val = (acc[ot][nt][r] + bv[r] - mv[r]) * s + tv[r];
                    Vb[(size_t)(o0 + r) * N + n] = (__bf16)val;
                }
            }
        }
    }
}

// ---------------------------------------------------------------------------
// Stage 2: flash attention with kv-split. Each block: 128 q x (N/KSPLIT) kv.
// Transposed logits S^T[kv][q] (softmax over rows -> per-lane stats, 2 shfl).
// Writes unnormalized U[c][q] partials + (m,l) per q; gfa_reduce combines.
// grid (N/128, KSPLIT, B), block 256 (4 waves x 32 q).
// LDS 36864B -> 4 blocks/CU (16 waves/CU).
// ---------------------------------------------------------------------------
__global__ __launch_bounds__(256, 4) void gfa_stage2(
    const __bf16* __restrict__ Q, const __bf16* __restrict__ K,
    const __bf16* __restrict__ V,
    float* __restrict__ Upart, float* __restrict__ stats, int N)
{
    const int tid  = threadIdx.x;
    const int w    = tid >> 6;
    const int lane = tid & 63;
    const int l15  = lane & 15;
    const int quad = lane >> 4;
    const int qt   = blockIdx.x;
    const int sp   = blockIdx.y;
    const int b    = blockIdx.z;
    const int qb0  = qt * 128 + w * 32;
    const int QT   = N >> 6;           // 64-q output tiles

    __shared__ __align__(16) char lds[36864];
    char* Kt = lds;                    // [64 kv][144B]
    char* Vt = lds + 9216;             // [64 c ][144B]
    char* Pw = lds + 18432 + w * 4608; // per-wave, 2 strips [16 q][144B]

    const __bf16* Qg = Q + (size_t)b * N * CDIM;
    const __bf16* Kg = K + (size_t)b * N * CDIM;
    const __bf16* Vg = V + (size_t)b * CDIM * N;
    const int kvb = sp * (N / KSPLIT);

    bf16x8 qf[2][2];   // [nt][kc]
#pragma unroll
    for (int nt = 0; nt < 2; nt++)
#pragma unroll
        for (int kc = 0; kc < 2; kc++)
            qf[nt][kc] = *(const bf16x8*)(Qg + (size_t)(qb0 + nt * 16 + l15) * CDIM + kc * 32 + quad * 8);

    f32x4 acc[2][4];
#pragma unroll
    for (int nt = 0; nt < 2; nt++)
#pragma unroll
        for (int tc = 0; tc < 4; tc++) acc[nt][tc] = (f32x4){0.f, 0.f, 0.f, 0.f};
    float m_run[2] = {-INFINITY, -INFINITY};
    float l_run[2] = {0.f, 0.f};

    for (int it = 0; it < N / KSPLIT / TK; it++) {
        const int kv0 = kvb + it * TK;
        __syncthreads();
#pragma unroll
        for (int p = 0; p < 2; p++) {   // K tile: 64 x 128B
            int idx = p * 256 + tid;
            int r = idx >> 3, c16 = idx & 7;
            *(int4*)(Kt + r * 144 + c16 * 16) =
                *(const int4*)((const char*)Kg + (size_t)(kv0 + r) * CDIM * 2 + c16 * 16);
        }
#pragma unroll
        for (int p = 0; p < 2; p++) {   // V tile: 64 x 128B
            int idx = p * 256 + tid;
            int r = idx >> 3, c16 = idx & 7;
            *(int4*)(Vt + r * 144 + c16 * 16) =
                *(const int4*)((const char*)Vg + ((size_t)r * N + kv0) * 2 + c16 * 16);
        }
        __syncthreads();

#pragma unroll
        for (int nt = 0; nt < 2; nt++) {
            f32x4 lt[4];
#pragma unroll
            for (int t = 0; t < 4; t++) {
                f32x4 a = (f32x4){0.f, 0.f, 0.f, 0.f};
#pragma unroll
                for (int kc = 0; kc < 2; kc++) {
                    bf16x8 kf = *(const bf16x8*)(Kt + (16 * t + l15) * 144 + kc * 64 + quad * 16);
                    a = __builtin_amdgcn_mfma_f32_16x16x32_bf16(kf, qf[nt][kc], a, 0, 0, 0);
                }
                lt[t] = a;
            }
            float mx = -INFINITY;
#pragma unroll
            for (int t = 0; t < 4; t++)
#pragma unroll
                for (int r = 0; r < 4; r++) mx = fmaxf(mx, lt[t][r]);
            mx = fmaxf(mx, __shfl_xor(mx, 16));
            mx = fmaxf(mx, __shfl_xor(mx, 32));
            float m_new = fmaxf(m_run[nt], mx);
            float scale = __expf(m_run[nt] - m_new);
            float s = 0.f;
#pragma unroll
            for (int t = 0; t < 4; t++) {
                bf16x4 pb;
#pragma unroll
                for (int r = 0; r < 4; r++) {
                    float p = __expf(lt[t][r] - m_new);
                    s += p;
                    pb[r] = (__bf16)p;
                }
                *(bf16x4*)(Pw + nt * 2304 + l15 * 144 + (16 * t + quad * 4) * 2) = pb;
            }
            s += __shfl_xor(s, 16);
            s += __shfl_xor(s, 32);
            l_run[nt] = l_run[nt] * scale + s;
            m_run[nt] = m_new;
#pragma unroll
            for (int tc = 0; tc < 4; tc++)
#pragma unroll
                for (int r = 0; r < 4; r++) acc[nt][tc][r] *= scale;
        }

        // PV: V-frag shared across both q-subtiles
#pragma unroll
        for (int ks = 0; ks < 2; ks++) {
            bf16x8 pf0 = *(const bf16x8*)(Pw + 0    + l15 * 144 + ks * 64 + quad * 16);
            bf16x8 pf1 = *(const bf16x8*)(Pw + 2304 + l15 * 144 + ks * 64 + quad * 16);
#pragma unroll
            for (int tc = 0; tc < 4; tc++) {
                bf16x8 vf = *(const bf16x8*)(Vt + (16 * tc + l15) * 144 + ks * 64 + quad * 16);
                acc[0][tc] = __builtin_amdgcn_mfma_f32_16x16x32_bf16(vf, pf0, acc[0][tc], 0, 0, 0);
                acc[1][tc] = __builtin_amdgcn_mfma_f32_16x16x32_bf16(vf, pf1, acc[1][tc], 0, 0, 0);
            }
        }
    }

    // write partials: U[c][q] per 64-q tile; waves 0,1 -> tile 2qt, waves 2,3 -> 2qt+1
    const int qt64 = qt * 2 + (w >> 1);
    float* Ub = Upart + ((size_t)(b * KSPLIT + sp) * QT + qt64) * 4096;
    float* Sb = stats + ((size_t)(b * KSPLIT + sp) * QT + qt64) * 128;
#pragma unroll
    for (int nt = 0; nt < 2; nt++) {
        int qq = (w & 1) * 32 + nt * 16 + l15;
#pragma unroll
        for (int tc = 0; tc < 4; tc++)
#pragma unroll
            for (int r = 0; r < 4; r++) {
                int c = tc * 16 + quad * 4 + r;
                Ub[c * 64 + qq] = acc[nt][tc][r];
            }
        if (quad == 0)
            *(float2*)&Sb[qq * 2] = make_float2(m_run[nt], l_run[nt]);
    }
}

// ---------------------------------------------------------------------------
// Reduce: combine KSPLIT partials, fuse residual epilogue.
// grid (N/64, B), block 256. thread -> q = tid&63, c-group = tid>>6 (16 c).
// ---------------------------------------------------------------------------
__global__ __launch_bounds__(256) void gfa_reduce(
    const float* __restrict__ feature, const float* __restrict__ alpha_p,
    const float* __restrict__ Upart, const float* __restrict__ stats,
    float* __restrict__ out, int N)
{
    const int qt = blockIdx.x;
    const int b  = blockIdx.y;
    const int q  = threadIdx.x & 63;
    const int cg = threadIdx.x >> 6;
    const int QT = N >> 6;

    float ms[KSPLIT], ls[KSPLIT];
    float M = -INFINITY;
#pragma unroll
    for (int s = 0; s < KSPLIT; s++) {
        float2 st = *(const float2*)&stats[((size_t)(b * KSPLIT + s) * QT + qt) * 128 + q * 2];
        ms[s] = st.x; ls[s] = st.y;
        M = fmaxf(M, ms[s]);
    }
    float L = 0.f, wsc[KSPLIT];
#pragma unroll
    for (int s = 0; s < KSPLIT; s++) {
        wsc[s] = __expf(ms[s] - M);
        L += ls[s] * wsc[s];
    }
    float scale = 2.f * alpha_p[0] / L;
    const int n = qt * 64 + q;

#pragma unroll
    for (int i = 0; i < 16; i++) {
        int c = cg * 16 + i;
        float u = 0.f;
#pragma unroll
        for (int s = 0; s < KSPLIT; s++)
            u += Upart[((size_t)(b * KSPLIT + s) * QT + qt) * 4096 + c * 64 + q] * wsc[s];
        size_t gi = ((size_t)b * CDIM + c) * N + n;
        out[gi] = 2.f * feature[gi] + scale * u;
    }
}

// ---------------------------------------------------------------------------
extern "C" void kernel_launch(void* const* d_in, const int* in_sizes, int n_in,
                              void* d_out, int out_size, void* d_ws, size_t ws_size,
                              hipStream_t stream) {
    const float* feature = (const float*)d_in[0];
    const float* wa   = (const float*)d_in[1];
    const float* ba   = (const float*)d_in[2];
    const float* wb   = (const float*)d_in[3];
    const float* bb   = (const float*)d_in[4];
    const float* wm   = (const float*)d_in[5];
    const float* bm   = (const float*)d_in[6];
    const float* gma  = (const float*)d_in[7];
    const float* bta  = (const float*)d_in[8];
    const float* mean = (const float*)d_in[9];
    const float* var  = (const float*)d_in[10];
    const float* alpha = (const float*)d_in[11];
    const int N = in_sizes[0] / (BATCH * CDIM);   // 8192

    __bf16* Q = (__bf16*)d_ws;
    __bf16* K = Q + (size_t)BATCH * N * CDIM;
    __bf16* V = K + (size_t)BATCH * N * CDIM;
    float* Upart = (float*)(V + (size_t)BATCH * N * CDIM);
    float* stats = Upart + (size_t)BATCH * KSPLIT * (N / 64) * 4096;

    dim3 g1(N / 128, 3, BATCH);
    gfa_stage1<<<g1, 256, 0, stream>>>(feature, wa, ba, wb, bb, wm, bm,
                                       gma, bta, mean, var, Q, K, V, N);
    dim3 g2(N / 128, KSPLIT, BATCH);
    gfa_stage2<<<g2, 256, 0, stream>>>(Q, K, V, Upart, stats, N);
    dim3 g3(N / 64, BATCH);
    gfa_reduce<<<g3, 256, 0, stream>>>(feature, alpha, Upart, stats, (float*)d_out, N);
}